// Round 10
// baseline (35.048 us; speedup 1.0000x reference)
//
#include <hip/hip_runtime.h>

// Problem constants: B=4, H=64, W=64, d=V=O=64, HW=4096
#define HW 4096
#define EPSF 1e-7f

// ws layout (float offsets):
#define WS_S1  0         // [4*64*64]  S1[b,l,j]
#define WS_S2P 16384     // [4*64*64]  S2 partial per l
#define WS_QSP 32768     // [4*64*64]  Qsum partial per l
#define WS_Z   49152     // [4*64*64]  z[b,h,j] (pre-norm)
#define WS_ZO  65536     // [4*64*64]  Zo (post-relu)
#define WS_ABC 81920     // A[64],B[64],C[64]
#define WS_CTR 82176     // int[8]: per-batch z-completion counters (4 used)

// sum-reduce a float4 across the 4 16-lane groups of a wave (offsets 16,32)
__device__ __forceinline__ void xr4(float4& v) {
    v.x += __shfl_xor(v.x, 16); v.y += __shfl_xor(v.y, 16);
    v.z += __shfl_xor(v.z, 16); v.w += __shfl_xor(v.w, 16);
    v.x += __shfl_xor(v.x, 32); v.y += __shfl_xor(v.y, 32);
    v.z += __shfl_xor(v.z, 32); v.w += __shfl_xor(v.w, 32);
}

// Row softmax helper over 16 lanes x 4 cols: returns Q4 for this row chunk.
__device__ __forceinline__ float4 row_softmax(float4 x, float4 A4, float4 B4, float4 C4) {
    float4 q;
    q.x = fmaf(fmaf(A4.x, x.x, -2.0f * B4.x), x.x, C4.x);
    q.y = fmaf(fmaf(A4.y, x.y, -2.0f * B4.y), x.y, C4.y);
    q.z = fmaf(fmaf(A4.z, x.z, -2.0f * B4.z), x.z, C4.z);
    q.w = fmaf(fmaf(A4.w, x.w, -2.0f * B4.w), x.w, C4.w);
    float m = fminf(fminf(q.x, q.y), fminf(q.z, q.w));
    m = fminf(m, __shfl_xor(m, 1)); m = fminf(m, __shfl_xor(m, 2));
    m = fminf(m, __shfl_xor(m, 4)); m = fminf(m, __shfl_xor(m, 8));
    float4 e;
    e.x = __expf(-0.5f * (q.x - m)); e.y = __expf(-0.5f * (q.y - m));
    e.z = __expf(-0.5f * (q.z - m)); e.w = __expf(-0.5f * (q.w - m));
    float s = e.x + e.y + e.z + e.w;
    s += __shfl_xor(s, 1); s += __shfl_xor(s, 2);
    s += __shfl_xor(s, 4); s += __shfl_xor(s, 8);
    float rs = 1.0f / s;
    float4 Q4; Q4.x = e.x * rs; Q4.y = e.y * rs; Q4.z = e.z * rs; Q4.w = e.w * rs;
    return Q4;
}

// ---------------------------------------------------------------------------
// kA: grid 256 = (b,l), 512 threads. ABC + Q rows (regs) + S1/S2p/Qsp.
// Block 0 publishes ABC and zeroes the kBCD barrier counters.
__global__ __launch_bounds__(512) void kA(const float* __restrict__ X,
                                          const float* __restrict__ Wm,
                                          const float* __restrict__ var,
                                          float* __restrict__ ws) {
    int b = blockIdx.x >> 6, l = blockIdx.x & 63;
    int t = threadIdx.x;
    int wv = t >> 6, j = t & 63;
    int lane16 = t & 15, r0 = t >> 4;   // r0 in 0..31
    __shared__ float4 red4[3][8][16];
    __shared__ float4 abc4[3][16];

    if (blockIdx.x == 0 && t < 8) ((int*)(ws + WS_CTR))[t] = 0;

    // ---- phase 1: ABC constants (float4), inv/wiv in registers ----
    float4 iv0, iv1, wiv0, wiv1;
    float4 aA = {0,0,0,0}, aB = {0,0,0,0}, aC = {0,0,0,0};
    {
        float4 v4 = *(const float4*)&var[r0 * 64 + lane16 * 4];
        float4 w4 = *(const float4*)&Wm[r0 * 64 + lane16 * 4];
        iv0.x = 1.0f / v4.x; iv0.y = 1.0f / v4.y; iv0.z = 1.0f / v4.z; iv0.w = 1.0f / v4.w;
        wiv0.x = w4.x * iv0.x; wiv0.y = w4.y * iv0.y; wiv0.z = w4.z * iv0.z; wiv0.w = w4.w * iv0.w;
        aA.x = fmaf(iv0.x, iv0.x, aA.x); aA.y = fmaf(iv0.y, iv0.y, aA.y);
        aA.z = fmaf(iv0.z, iv0.z, aA.z); aA.w = fmaf(iv0.w, iv0.w, aA.w);
        aB.x = fmaf(wiv0.x, iv0.x, aB.x); aB.y = fmaf(wiv0.y, iv0.y, aB.y);
        aB.z = fmaf(wiv0.z, iv0.z, aB.z); aB.w = fmaf(wiv0.w, iv0.w, aB.w);
        aC.x = fmaf(wiv0.x, wiv0.x, aC.x); aC.y = fmaf(wiv0.y, wiv0.y, aC.y);
        aC.z = fmaf(wiv0.z, wiv0.z, aC.z); aC.w = fmaf(wiv0.w, wiv0.w, aC.w);
    }
    {
        int i = r0 + 32;
        float4 v4 = *(const float4*)&var[i * 64 + lane16 * 4];
        float4 w4 = *(const float4*)&Wm[i * 64 + lane16 * 4];
        iv1.x = 1.0f / v4.x; iv1.y = 1.0f / v4.y; iv1.z = 1.0f / v4.z; iv1.w = 1.0f / v4.w;
        wiv1.x = w4.x * iv1.x; wiv1.y = w4.y * iv1.y; wiv1.z = w4.z * iv1.z; wiv1.w = w4.w * iv1.w;
        aA.x = fmaf(iv1.x, iv1.x, aA.x); aA.y = fmaf(iv1.y, iv1.y, aA.y);
        aA.z = fmaf(iv1.z, iv1.z, aA.z); aA.w = fmaf(iv1.w, iv1.w, aA.w);
        aB.x = fmaf(wiv1.x, iv1.x, aB.x); aB.y = fmaf(wiv1.y, iv1.y, aB.y);
        aB.z = fmaf(wiv1.z, iv1.z, aB.z); aB.w = fmaf(wiv1.w, iv1.w, aB.w);
        aC.x = fmaf(wiv1.x, wiv1.x, aC.x); aC.y = fmaf(wiv1.y, wiv1.y, aC.y);
        aC.z = fmaf(wiv1.z, wiv1.z, aC.z); aC.w = fmaf(wiv1.w, wiv1.w, aC.w);
    }
    xr4(aA); xr4(aB); xr4(aC);
    if ((t & 63) < 16) { red4[0][wv][lane16] = aA; red4[1][wv][lane16] = aB; red4[2][wv][lane16] = aC; }
    __syncthreads();
    if (t < 16) {
        float4 A = {0,0,0,0}, Bq = {0,0,0,0}, C = {0,0,0,0};
#pragma unroll
        for (int w = 0; w < 8; w++) {
            float4 a = red4[0][w][t], bb = red4[1][w][t], c = red4[2][w][t];
            A.x += a.x; A.y += a.y; A.z += a.z; A.w += a.w;
            Bq.x += bb.x; Bq.y += bb.y; Bq.z += bb.z; Bq.w += bb.w;
            C.x += c.x; C.y += c.y; C.z += c.z; C.w += c.w;
        }
        abc4[0][t] = A; abc4[1][t] = Bq; abc4[2][t] = C;
        if (blockIdx.x == 0) {
            *(float4*)&ws[WS_ABC + t * 4]       = A;
            *(float4*)&ws[WS_ABC + 64 + t * 4]  = Bq;
            *(float4*)&ws[WS_ABC + 128 + t * 4] = C;
        }
    }
    __syncthreads();
    float4 A4 = abc4[0][lane16], B4 = abc4[1][lane16], C4 = abc4[2][lane16];

    // ---- phase 2: Q rows (regs) + S1/S2/Qsum partials ----
    float4 s1 = {0,0,0,0}, s2 = {0,0,0,0}, qsm = {0,0,0,0};
    {
        int n = l * 64 + r0;
        float4 x = *(const float4*)&X[((size_t)(b * HW) + n) * 64 + lane16 * 4];
        float4 Q4 = row_softmax(x, A4, B4, C4);
        s1.x = fmaf(iv0.x, Q4.x, s1.x); s1.y = fmaf(iv0.y, Q4.y, s1.y);
        s1.z = fmaf(iv0.z, Q4.z, s1.z); s1.w = fmaf(iv0.w, Q4.w, s1.w);
        s2.x = fmaf(wiv0.x, Q4.x, s2.x); s2.y = fmaf(wiv0.y, Q4.y, s2.y);
        s2.z = fmaf(wiv0.z, Q4.z, s2.z); s2.w = fmaf(wiv0.w, Q4.w, s2.w);
        qsm.x += Q4.x; qsm.y += Q4.y; qsm.z += Q4.z; qsm.w += Q4.w;
    }
    {
        int n = l * 64 + r0 + 32;
        float4 x = *(const float4*)&X[((size_t)(b * HW) + n) * 64 + lane16 * 4];
        float4 Q4 = row_softmax(x, A4, B4, C4);
        s1.x = fmaf(iv1.x, Q4.x, s1.x); s1.y = fmaf(iv1.y, Q4.y, s1.y);
        s1.z = fmaf(iv1.z, Q4.z, s1.z); s1.w = fmaf(iv1.w, Q4.w, s1.w);
        s2.x = fmaf(wiv1.x, Q4.x, s2.x); s2.y = fmaf(wiv1.y, Q4.y, s2.y);
        s2.z = fmaf(wiv1.z, Q4.z, s2.z); s2.w = fmaf(wiv1.w, Q4.w, s2.w);
        qsm.x += Q4.x; qsm.y += Q4.y; qsm.z += Q4.z; qsm.w += Q4.w;
    }
    xr4(s1); xr4(s2); xr4(qsm);
    __syncthreads();
    if ((t & 63) < 16) { red4[0][wv][lane16] = s1; red4[1][wv][lane16] = s2; red4[2][wv][lane16] = qsm; }
    __syncthreads();
    if (t < 64) {
        int jg = j >> 2, cc = j & 3;
        float t0 = 0.f, t1 = 0.f, t2 = 0.f;
#pragma unroll
        for (int w = 0; w < 8; w++) {
            t0 += ((const float*)&red4[0][w][jg])[cc];
            t1 += ((const float*)&red4[1][w][jg])[cc];
            t2 += ((const float*)&red4[2][w][jg])[cc];
        }
        int idx = (b * 64 + l) * 64 + j;
        ws[WS_S1  + idx] = t0;
        ws[WS_S2P + idx] = t1;
        ws[WS_QSP + idx] = t2;
    }
}

// ---------------------------------------------------------------------------
// kBCD: grid 512, 512 threads.
//   Blocks 0..255  = B-role (b,h): compute z, release, exit (no spin).
//   Blocks 256..511 = CD-role (b,v): relaxed-spin until batch z complete,
//   one acquire fence, then the proven kCD body.
struct BRole { float4 red4[3][8][16]; };
struct CDRole {
    float zl[64][65]; float wl[64][65];
    float red[8][64];
    float sN[64]; float sin2[64]; float ghat[64]; float yv[64];
};
union SMU { BRole b; CDRole c; };

__global__ __launch_bounds__(512) void kBCD(const float* __restrict__ X,
                                            const float* __restrict__ weight,
                                            float* __restrict__ ws) {
    __shared__ SMU sm;
    int* ctr = (int*)(ws + WS_CTR);
    const int t = threadIdx.x;

    if (blockIdx.x < 256) {
        // ---------------- B role: z[b,h,:] ----------------
        int b = blockIdx.x >> 6, h = blockIdx.x & 63;
        int wv = t >> 6, j = t & 63;
        int lane16 = t & 15, lg = t >> 4;
        float4 acc = {0,0,0,0}, ps2 = {0,0,0,0}, pqs = {0,0,0,0};
#pragma unroll
        for (int half = 0; half < 2; half++) {
            int l = lg + half * 32;
            float4 x  = *(const float4*)&X[((size_t)(b * HW) + h * 64 + l) * 64 + lane16 * 4];
            int idx = (b * 64 + l) * 64 + lane16 * 4;
            float4 s1 = *(const float4*)&ws[WS_S1 + idx];
            float4 a2 = *(const float4*)&ws[WS_S2P + idx];
            float4 a3 = *(const float4*)&ws[WS_QSP + idx];
            acc.x = fmaf(x.x, s1.x, acc.x); acc.y = fmaf(x.y, s1.y, acc.y);
            acc.z = fmaf(x.z, s1.z, acc.z); acc.w = fmaf(x.w, s1.w, acc.w);
            ps2.x += a2.x; ps2.y += a2.y; ps2.z += a2.z; ps2.w += a2.w;
            pqs.x += a3.x; pqs.y += a3.y; pqs.z += a3.z; pqs.w += a3.w;
        }
        xr4(acc); xr4(ps2); xr4(pqs);
        if ((t & 63) < 16) {
            sm.b.red4[0][wv][lane16] = acc; sm.b.red4[1][wv][lane16] = ps2; sm.b.red4[2][wv][lane16] = pqs;
        }
        __syncthreads();
        if (t < 64) {
            int jg = j >> 2, cc = j & 3;
            float a = 0.f, s2 = 0.f, q = 0.f;
#pragma unroll
            for (int w = 0; w < 8; w++) {
                a  += ((const float*)&sm.b.red4[0][w][jg])[cc];
                s2 += ((const float*)&sm.b.red4[1][w][jg])[cc];
                q  += ((const float*)&sm.b.red4[2][w][jg])[cc];
            }
            ws[WS_Z + (b * 64 + h) * 64 + j] = (a - s2 + EPSF) / (q + EPSF);
        }
        __syncthreads();                 // drain z stores (vmcnt 0 at barrier)
        if (t == 0) {
            __threadfence();             // one release flush per producer block
            __hip_atomic_fetch_add(ctr + b, 1, __ATOMIC_RELAXED, __HIP_MEMORY_SCOPE_AGENT);
        }
        return;
    }

    // ---------------- CD role: Zo[v=s, :] for batch b ----------------
    int m = blockIdx.x - 256;
    int b = m >> 6, v = m & 63;
    int w8 = t >> 6, j = t & 63;
    if (t == 0) {
        while (__hip_atomic_load(ctr + b, __ATOMIC_RELAXED, __HIP_MEMORY_SCOPE_AGENT) < 64) {
            __builtin_amdgcn_s_sleep(32);   // ~2048 cyc between relaxed polls
        }
        __threadfence();                    // one acquire invalidate per consumer block
    }
    __syncthreads();

#pragma unroll
    for (int k = 0; k < 2; k++) {
        int fidx = (k * 512 + t) * 4;
        int r = fidx >> 6, cc = fidx & 63;
        float4 zv = *(const float4*)&ws[WS_Z + b * 4096 + fidx];
        float4 wv = *(const float4*)&weight[fidx];
        sm.c.zl[r][cc] = zv.x; sm.c.zl[r][cc+1] = zv.y; sm.c.zl[r][cc+2] = zv.z; sm.c.zl[r][cc+3] = zv.w;
        sm.c.wl[r][cc] = wv.x; sm.c.wl[r][cc+1] = wv.y; sm.c.wl[r][cc+2] = wv.z; sm.c.wl[r][cc+3] = wv.w;
    }
    __syncthreads();
    {
        float na = 0.f;
#pragma unroll
        for (int k = 0; k < 8; k++) { float zz = sm.c.zl[w8 * 8 + k][j]; na = fmaf(zz, zz, na); }
        sm.c.red[w8][j] = na;
        __syncthreads();
        if (t < 64) {
            float s = 0.f;
#pragma unroll
            for (int tt = 0; tt < 8; tt++) s += sm.c.red[tt][j];
            sm.c.sN[j] = s; sm.c.sin2[j] = 1.0f / (s * s);
        }
        __syncthreads();
    }
    {
        float g = 0.f;
#pragma unroll
        for (int k = 0; k < 8; k++) { int d = w8 * 8 + k; g = fmaf(sm.c.zl[d][v], sm.c.zl[d][j], g); }
        sm.c.red[w8][j] = g;
        __syncthreads();
        if (t < 64) {
            float s = 0.f;
#pragma unroll
            for (int tt = 0; tt < 8; tt++) s += sm.c.red[tt][j];
            sm.c.ghat[j] = s * sm.c.sin2[j];
        }
        __syncthreads();
    }
    {
        float y = 0.f;
#pragma unroll
        for (int k = 0; k < 8; k++) { int u = w8 * 8 + k; y = fmaf(sm.c.ghat[u], sm.c.zl[j][u], y); }
        sm.c.red[w8][j] = y;
        __syncthreads();
        if (t < 64) {
            float s = 0.f;
#pragma unroll
            for (int tt = 0; tt < 8; tt++) s += sm.c.red[tt][j];
            sm.c.yv[j] = s;
        }
        __syncthreads();
    }
    {
        float a = 0.f;
#pragma unroll
        for (int k = 0; k < 8; k++) { int d = w8 * 8 + k; a = fmaf(sm.c.yv[d], sm.c.wl[d][j], a); }
        sm.c.red[w8][j] = a;
        __syncthreads();
        if (t < 64) {
            float s = 0.f;
#pragma unroll
            for (int tt = 0; tt < 8; tt++) s += sm.c.red[tt][j];
            float r = s / sm.c.sN[v];
            r = r > 0.f ? r : 0.f;
            ws[WS_ZO + (b * 64 + v) * 64 + j] = r;
        }
    }
}

// ---------------------------------------------------------------------------
// kF: grid 256 = (b, tile), 512 threads. Recompute Q from X + ABC, then
// out = Q * Zo with transposed coalesced writes.
__global__ __launch_bounds__(512) void kF(const float* __restrict__ X,
                                          const float* __restrict__ ws,
                                          float* __restrict__ out) {
    int b = blockIdx.x >> 6, tb = blockIdx.x & 63;
    int nbase = tb * 64;
    int t = threadIdx.x;
    int w8 = t >> 6, j = t & 63;
    int lane16 = t & 15, r0 = t >> 4;
    int o8 = w8 * 8;
    __shared__ float qs[64][65];
    __shared__ __align__(16) float zo[64][68];

    float4 A4 = *(const float4*)&ws[WS_ABC + lane16 * 4];
    float4 B4 = *(const float4*)&ws[WS_ABC + 64 + lane16 * 4];
    float4 C4 = *(const float4*)&ws[WS_ABC + 128 + lane16 * 4];

#pragma unroll
    for (int k = 0; k < 2; k++) {
        int fidx = (k * 512 + t) * 4;
        int r = fidx >> 6, cc = fidx & 63;
        float4 zv = *(const float4*)&ws[WS_ZO + b * 4096 + fidx];
        zo[r][cc] = zv.x; zo[r][cc+1] = zv.y; zo[r][cc+2] = zv.z; zo[r][cc+3] = zv.w;
    }
#pragma unroll
    for (int half = 0; half < 2; half++) {
        int rr = r0 + half * 32;
        int n = nbase + rr;
        float4 x = *(const float4*)&X[((size_t)(b * HW) + n) * 64 + lane16 * 4];
        float4 Q4 = row_softmax(x, A4, B4, C4);
        qs[rr][lane16 * 4]     = Q4.x;
        qs[rr][lane16 * 4 + 1] = Q4.y;
        qs[rr][lane16 * 4 + 2] = Q4.z;
        qs[rr][lane16 * 4 + 3] = Q4.w;
    }
    __syncthreads();

    float acc[8];
#pragma unroll
    for (int k = 0; k < 8; k++) acc[k] = 0.f;
#pragma unroll
    for (int v = 0; v < 64; v++) {
        float qv = qs[j][v];
        float4 z0 = *(const float4*)&zo[v][o8];
        float4 z1 = *(const float4*)&zo[v][o8 + 4];
        acc[0] = fmaf(qv, z0.x, acc[0]);
        acc[1] = fmaf(qv, z0.y, acc[1]);
        acc[2] = fmaf(qv, z0.z, acc[2]);
        acc[3] = fmaf(qv, z0.w, acc[3]);
        acc[4] = fmaf(qv, z1.x, acc[4]);
        acc[5] = fmaf(qv, z1.y, acc[5]);
        acc[6] = fmaf(qv, z1.z, acc[6]);
        acc[7] = fmaf(qv, z1.w, acc[7]);
    }
#pragma unroll
    for (int k = 0; k < 8; k++) {
        int o = o8 + k;
        out[(size_t)(b * 64 + o) * HW + nbase + j] = acc[k];
    }
}

extern "C" void kernel_launch(void* const* d_in, const int* in_sizes, int n_in,
                              void* d_out, int out_size, void* d_ws, size_t ws_size,
                              hipStream_t stream) {
    const float* X      = (const float*)d_in[0];
    const float* Wm     = (const float*)d_in[1];
    const float* var    = (const float*)d_in[2];
    const float* weight = (const float*)d_in[3];
    float* ws  = (float*)d_ws;
    float* out = (float*)d_out;

    kA  <<<256, 512, 0, stream>>>(X, Wm, var, ws);
    kBCD<<<512, 512, 0, stream>>>(X, weight, ws);
    kF  <<<256, 512, 0, stream>>>(X, ws, out);
}

// Round 11
// 21.249 us; speedup vs baseline: 1.6494x; 1.6494x over previous
//
#include <hip/hip_runtime.h>

// Problem constants: B=4, H=64, W=64, d=V=O=64, HW=4096
#define HW 4096
#define EPSF 1e-7f

// ws layout (float offsets):
#define WS_S1  0         // [4*64*64]  S1[b,l,j]
#define WS_S2P 16384     // [4*64*64]  S2 partial per l
#define WS_QSP 32768     // [4*64*64]  Qsum partial per l
#define WS_Z   49152     // [4*64*64]  z[b,h,j] (pre-norm)
#define WS_ZO  65536     // [4*64*64]  Zo (post-relu)
#define WS_Q   81920     // [4*4096*64] Q

// sum-reduce a float4 across the 4 16-lane groups of a wave (offsets 16,32)
__device__ __forceinline__ void xr4(float4& v) {
    v.x += __shfl_xor(v.x, 16); v.y += __shfl_xor(v.y, 16);
    v.z += __shfl_xor(v.z, 16); v.w += __shfl_xor(v.w, 16);
    v.x += __shfl_xor(v.x, 32); v.y += __shfl_xor(v.y, 32);
    v.z += __shfl_xor(v.z, 32); v.w += __shfl_xor(v.w, 32);
}

// ---------------------------------------------------------------------------
// kA: grid 256 = (b,l), 512 threads. ABC + Q rows (float4) + S1/S2p/Qsp.
// Phase 2: each row handled by 16 lanes x 4 columns.
__global__ __launch_bounds__(512) void kA(const float* __restrict__ X,
                                          const float* __restrict__ Wm,
                                          const float* __restrict__ var,
                                          float* __restrict__ ws) {
    int b = blockIdx.x >> 6, l = blockIdx.x & 63;
    int t = threadIdx.x;
    int wv = t >> 6, j = t & 63;       // phase-1 mapping
    int lane16 = t & 15, r0 = t >> 4;  // phase-2 mapping (r0 in 0..31)

    __shared__ __align__(16) float invl[64][64];
    __shared__ __align__(16) float wivl[64][64];
    __shared__ __align__(16) float abcA[64];
    __shared__ __align__(16) float abcB[64];
    __shared__ __align__(16) float abcC[64];
    __shared__ float red[3][8][64];
    __shared__ float4 red4[3][8][16];

    // ---- phase 1: inv/wiv into LDS, ABC column constants ----
    {
        float a = 0.f, bq = 0.f, c = 0.f;
#pragma unroll
        for (int k = 0; k < 8; k++) {
            int i = wv * 8 + k;
            float v   = var[i * 64 + j];
            float wvv = Wm[i * 64 + j];
            float iv  = 1.0f / v;
            invl[i][j] = iv; wivl[i][j] = wvv * iv;
            float iv2 = iv * iv;
            a += iv2; bq += wvv * iv2; c += wvv * wvv * iv2;
        }
        red[0][wv][j] = a; red[1][wv][j] = bq; red[2][wv][j] = c;
    }
    __syncthreads();
    if (t < 64) {
        float t0 = 0.f, t1 = 0.f, t2 = 0.f;
#pragma unroll
        for (int w = 0; w < 8; w++) { t0 += red[0][w][j]; t1 += red[1][w][j]; t2 += red[2][w][j]; }
        abcA[j] = t0; abcB[j] = t1; abcC[j] = t2;
    }
    __syncthreads();

    // ---- phase 2: Q rows + S1/S2/Qsum partials ----
    float4 A4 = *(const float4*)&abcA[lane16 * 4];
    float4 B4 = *(const float4*)&abcB[lane16 * 4];
    float4 C4 = *(const float4*)&abcC[lane16 * 4];
    float4 s1 = {0,0,0,0}, s2 = {0,0,0,0}, qsm = {0,0,0,0};
#pragma unroll
    for (int half = 0; half < 2; half++) {
        int rr = r0 + half * 32;
        int n  = l * 64 + rr;
        float4 x = *(const float4*)&X[((size_t)(b * HW) + n) * 64 + lane16 * 4];
        float4 q;
        q.x = fmaf(fmaf(A4.x, x.x, -2.0f * B4.x), x.x, C4.x);
        q.y = fmaf(fmaf(A4.y, x.y, -2.0f * B4.y), x.y, C4.y);
        q.z = fmaf(fmaf(A4.z, x.z, -2.0f * B4.z), x.z, C4.z);
        q.w = fmaf(fmaf(A4.w, x.w, -2.0f * B4.w), x.w, C4.w);
        float m = fminf(fminf(q.x, q.y), fminf(q.z, q.w));
        m = fminf(m, __shfl_xor(m, 1)); m = fminf(m, __shfl_xor(m, 2));
        m = fminf(m, __shfl_xor(m, 4)); m = fminf(m, __shfl_xor(m, 8));
        float4 e;
        e.x = __expf(-0.5f * (q.x - m)); e.y = __expf(-0.5f * (q.y - m));
        e.z = __expf(-0.5f * (q.z - m)); e.w = __expf(-0.5f * (q.w - m));
        float s = e.x + e.y + e.z + e.w;
        s += __shfl_xor(s, 1); s += __shfl_xor(s, 2);
        s += __shfl_xor(s, 4); s += __shfl_xor(s, 8);
        float rs = 1.0f / s;
        float4 Q4; Q4.x = e.x * rs; Q4.y = e.y * rs; Q4.z = e.z * rs; Q4.w = e.w * rs;
        *(float4*)&ws[WS_Q + ((size_t)(b * HW) + n) * 64 + lane16 * 4] = Q4;
        float4 iv4 = *(const float4*)&invl[rr][lane16 * 4];
        float4 wv4 = *(const float4*)&wivl[rr][lane16 * 4];
        s1.x = fmaf(iv4.x, Q4.x, s1.x); s1.y = fmaf(iv4.y, Q4.y, s1.y);
        s1.z = fmaf(iv4.z, Q4.z, s1.z); s1.w = fmaf(iv4.w, Q4.w, s1.w);
        s2.x = fmaf(wv4.x, Q4.x, s2.x); s2.y = fmaf(wv4.y, Q4.y, s2.y);
        s2.z = fmaf(wv4.z, Q4.z, s2.z); s2.w = fmaf(wv4.w, Q4.w, s2.w);
        qsm.x += Q4.x; qsm.y += Q4.y; qsm.z += Q4.z; qsm.w += Q4.w;
    }
    xr4(s1); xr4(s2); xr4(qsm);
    if ((t & 63) < 16) {
        red4[0][wv][lane16] = s1; red4[1][wv][lane16] = s2; red4[2][wv][lane16] = qsm;
    }
    __syncthreads();
    if (t < 64) {
        int jg = j >> 2, cc = j & 3;
        float t0 = 0.f, t1 = 0.f, t2 = 0.f;
#pragma unroll
        for (int w = 0; w < 8; w++) {
            t0 += ((const float*)&red4[0][w][jg])[cc];
            t1 += ((const float*)&red4[1][w][jg])[cc];
            t2 += ((const float*)&red4[2][w][jg])[cc];
        }
        int idx = (b * 64 + l) * 64 + j;
        ws[WS_S1  + idx] = t0;
        ws[WS_S2P + idx] = t1;
        ws[WS_QSP + idx] = t2;
    }
}

// ---------------------------------------------------------------------------
// kB: grid 256 = (b,h), 512 threads, float4 everywhere. z[b,h,j].
__global__ __launch_bounds__(512) void kB(const float* __restrict__ X,
                                          float* __restrict__ ws) {
    int b = blockIdx.x >> 6, h = blockIdx.x & 63;
    int t = threadIdx.x;
    int wv = t >> 6, j = t & 63;
    int lane16 = t & 15, lg = t >> 4;
    __shared__ float4 red4[3][8][16];
    float4 acc = {0,0,0,0}, ps2 = {0,0,0,0}, pqs = {0,0,0,0};
#pragma unroll
    for (int half = 0; half < 2; half++) {
        int l = lg + half * 32;
        float4 x  = *(const float4*)&X[((size_t)(b * HW) + h * 64 + l) * 64 + lane16 * 4];
        int idx = (b * 64 + l) * 64 + lane16 * 4;
        float4 s1 = *(const float4*)&ws[WS_S1 + idx];
        float4 a2 = *(const float4*)&ws[WS_S2P + idx];
        float4 a3 = *(const float4*)&ws[WS_QSP + idx];
        acc.x = fmaf(x.x, s1.x, acc.x); acc.y = fmaf(x.y, s1.y, acc.y);
        acc.z = fmaf(x.z, s1.z, acc.z); acc.w = fmaf(x.w, s1.w, acc.w);
        ps2.x += a2.x; ps2.y += a2.y; ps2.z += a2.z; ps2.w += a2.w;
        pqs.x += a3.x; pqs.y += a3.y; pqs.z += a3.z; pqs.w += a3.w;
    }
    xr4(acc); xr4(ps2); xr4(pqs);
    if ((t & 63) < 16) {
        red4[0][wv][lane16] = acc; red4[1][wv][lane16] = ps2; red4[2][wv][lane16] = pqs;
    }
    __syncthreads();
    if (t < 64) {
        int jg = j >> 2, cc = j & 3;
        float a = 0.f, s2 = 0.f, q = 0.f;
#pragma unroll
        for (int w = 0; w < 8; w++) {
            a  += ((const float*)&red4[0][w][jg])[cc];
            s2 += ((const float*)&red4[1][w][jg])[cc];
            q  += ((const float*)&red4[2][w][jg])[cc];
        }
        ws[WS_Z + (b * 64 + h) * 64 + j] = (a - s2 + EPSF) / (q + EPSF);
    }
}

// ---------------------------------------------------------------------------
// kCD: grid 256 = (b,v), 512 threads. z -> Zo (norm folded algebraically).
__global__ __launch_bounds__(512) void kCD(const float* __restrict__ weight,
                                           float* __restrict__ ws) {
    int b = blockIdx.x >> 6, v = blockIdx.x & 63;
    int w8 = threadIdx.x >> 6, j = threadIdx.x & 63;
    __shared__ float zl[64][65];
    __shared__ float wl[64][65];
    __shared__ float red[8][64];
    __shared__ float sN[64], sin2[64], ghat[64], yv[64];
#pragma unroll
    for (int k = 0; k < 2; k++) {
        int fidx = (k * 512 + threadIdx.x) * 4;
        int r = fidx >> 6, cc = fidx & 63;
        float4 zv = *(const float4*)&ws[WS_Z + b * 4096 + fidx];
        float4 wv = *(const float4*)&weight[fidx];
        zl[r][cc] = zv.x; zl[r][cc+1] = zv.y; zl[r][cc+2] = zv.z; zl[r][cc+3] = zv.w;
        wl[r][cc] = wv.x; wl[r][cc+1] = wv.y; wl[r][cc+2] = wv.z; wl[r][cc+3] = wv.w;
    }
    __syncthreads();
    {
        float na = 0.f;
#pragma unroll
        for (int k = 0; k < 8; k++) { float zz = zl[w8 * 8 + k][j]; na = fmaf(zz, zz, na); }
        red[w8][j] = na;
        __syncthreads();
        if (threadIdx.x < 64) {
            float s = 0.f;
#pragma unroll
            for (int tt = 0; tt < 8; tt++) s += red[tt][j];
            sN[j] = s; sin2[j] = 1.0f / (s * s);
        }
        __syncthreads();
    }
    {
        float g = 0.f;
#pragma unroll
        for (int k = 0; k < 8; k++) { int d = w8 * 8 + k; g = fmaf(zl[d][v], zl[d][j], g); }
        red[w8][j] = g;
        __syncthreads();
        if (threadIdx.x < 64) {
            float s = 0.f;
#pragma unroll
            for (int tt = 0; tt < 8; tt++) s += red[tt][j];
            ghat[j] = s * sin2[j];
        }
        __syncthreads();
    }
    {
        float y = 0.f;
#pragma unroll
        for (int k = 0; k < 8; k++) { int u = w8 * 8 + k; y = fmaf(ghat[u], zl[j][u], y); }
        red[w8][j] = y;
        __syncthreads();
        if (threadIdx.x < 64) {
            float s = 0.f;
#pragma unroll
            for (int tt = 0; tt < 8; tt++) s += red[tt][j];
            yv[j] = s;
        }
        __syncthreads();
    }
    {
        float a = 0.f;
#pragma unroll
        for (int k = 0; k < 8; k++) { int d = w8 * 8 + k; a = fmaf(yv[d], wl[d][j], a); }
        red[w8][j] = a;
        __syncthreads();
        if (threadIdx.x < 64) {
            float s = 0.f;
#pragma unroll
            for (int tt = 0; tt < 8; tt++) s += red[tt][j];
            float r = s / sN[v];
            r = r > 0.f ? r : 0.f;
            ws[WS_ZO + (b * 64 + v) * 64 + j] = r;
        }
    }
}

// ---------------------------------------------------------------------------
// kF: grid 256 = (b, tile), 512 threads. out = Q * Zo (transposed write).
__global__ __launch_bounds__(512) void kF(const float* __restrict__ ws,
                                          float* __restrict__ out) {
    int b = blockIdx.x >> 6, tb = blockIdx.x & 63;
    int nbase = tb * 64;
    int w8 = threadIdx.x >> 6, lane = threadIdx.x & 63;
    int o8 = w8 * 8;
    __shared__ float qs[64][65];
    __shared__ __align__(16) float zo[64][68];
#pragma unroll
    for (int k = 0; k < 2; k++) {
        int fidx = (k * 512 + threadIdx.x) * 4;
        int r = fidx >> 6, cc = fidx & 63;
        float4 qv = *(const float4*)&ws[WS_Q + ((size_t)(b * HW) + nbase + r) * 64 + cc];
        qs[r][cc] = qv.x; qs[r][cc+1] = qv.y; qs[r][cc+2] = qv.z; qs[r][cc+3] = qv.w;
        float4 zv = *(const float4*)&ws[WS_ZO + b * 4096 + fidx];
        zo[r][cc] = zv.x; zo[r][cc+1] = zv.y; zo[r][cc+2] = zv.z; zo[r][cc+3] = zv.w;
    }
    __syncthreads();
    float acc[8];
#pragma unroll
    for (int k = 0; k < 8; k++) acc[k] = 0.f;
#pragma unroll
    for (int v = 0; v < 64; v++) {
        float qv = qs[lane][v];                    // (lane+v)%32 distinct -> conflict-free
        float4 z0 = *(const float4*)&zo[v][o8];    // wave-uniform broadcast
        float4 z1 = *(const float4*)&zo[v][o8 + 4];
        acc[0] = fmaf(qv, z0.x, acc[0]);
        acc[1] = fmaf(qv, z0.y, acc[1]);
        acc[2] = fmaf(qv, z0.z, acc[2]);
        acc[3] = fmaf(qv, z0.w, acc[3]);
        acc[4] = fmaf(qv, z1.x, acc[4]);
        acc[5] = fmaf(qv, z1.y, acc[5]);
        acc[6] = fmaf(qv, z1.z, acc[6]);
        acc[7] = fmaf(qv, z1.w, acc[7]);
    }
#pragma unroll
    for (int k = 0; k < 8; k++) {
        int o = o8 + k;
        out[(size_t)(b * 64 + o) * HW + nbase + lane] = acc[k];
    }
}

extern "C" void kernel_launch(void* const* d_in, const int* in_sizes, int n_in,
                              void* d_out, int out_size, void* d_ws, size_t ws_size,
                              hipStream_t stream) {
    const float* X      = (const float*)d_in[0];
    const float* Wm     = (const float*)d_in[1];
    const float* var    = (const float*)d_in[2];
    const float* weight = (const float*)d_in[3];
    float* ws  = (float*)d_ws;
    float* out = (float*)d_out;

    kA <<<256, 512, 0, stream>>>(X, Wm, var, ws);
    kB <<<256, 512, 0, stream>>>(X, ws);
    kCD<<<256, 512, 0, stream>>>(weight, ws);
    kF <<<256, 512, 0, stream>>>(ws, out);
}